// Round 1
// baseline (794.853 us; speedup 1.0000x reference)
//
#include <hip/hip_runtime.h>
#include <hip/hip_bf16.h>
#include <math.h>

#define D 128

// ---------------- CSR build ----------------

__global__ void deg_kernel(const int* __restrict__ dst, int* __restrict__ deg, int E) {
    int e = blockIdx.x * blockDim.x + threadIdx.x;
    if (e < E) atomicAdd(&deg[dst[e]], 1);
}

// single block, 1024 threads: per-thread serial chunk + one LDS scan of the 1024 sums
__global__ void scan_kernel(const int* __restrict__ deg, int* __restrict__ row_ptr,
                            int* __restrict__ cursor, float* __restrict__ inv_deg, int n) {
    __shared__ int sums[1024];
    int tid = threadIdx.x;
    int chunk = (n + 1023) >> 10;
    int s = tid * chunk;
    int e = s + chunk; if (e > n) e = n;
    int local = 0;
    for (int i = s; i < e; ++i) local += deg[i];
    sums[tid] = local;
    __syncthreads();
    for (int off = 1; off < 1024; off <<= 1) {
        int t = (tid >= off) ? sums[tid - off] : 0;
        __syncthreads();
        sums[tid] += t;
        __syncthreads();
    }
    int run = sums[tid] - local;   // exclusive prefix of this thread's chunk
    for (int i = s; i < e; ++i) {
        int v = deg[i];
        row_ptr[i] = run;
        cursor[i]  = run;
        inv_deg[i] = 1.0f / (float)((v > 0) ? v : 1);
        run += v;
    }
    if (tid == 1023) row_ptr[n] = run;   // == E
}

__global__ void fill_kernel(const int* __restrict__ src, const int* __restrict__ dst,
                            int* __restrict__ cursor, int* __restrict__ col, int E) {
    int e = blockIdx.x * blockDim.x + threadIdx.x;
    if (e >= E) return;
    int pos = atomicAdd(&cursor[dst[e]], 1);
    col[pos] = src[e];
}

// ---------------- mean aggregation: one wave per node, float2/lane ----------------

__global__ void agg_kernel(const float* __restrict__ h, const int* __restrict__ row_ptr,
                           const int* __restrict__ col, const float* __restrict__ inv_deg,
                           float* __restrict__ out, int n) {
    int w = (blockIdx.x * blockDim.x + threadIdx.x) >> 6;
    int lane = threadIdx.x & 63;
    if (w >= n) return;
    int s = row_ptr[w], e = row_ptr[w + 1];
    float2 acc = make_float2(0.f, 0.f);
    for (int p = s; p < e; ++p) {
        int j = col[p];
        float2 v = ((const float2*)(h + (size_t)j * D))[lane];
        acc.x += v.x; acc.y += v.y;
    }
    float sc = inv_deg[w];
    ((float2*)(out + (size_t)w * D))[lane] = make_float2(acc.x * sc, acc.y * sc);
}

// ---------------- fused dual GEMM: out = relu(Aagg@Wl + Hin@Wr + bl) ----------------
// block tile 64 rows x 128 cols, 256 threads, 4x8 register micro-tile

__global__ __launch_bounds__(256) void sage_mm_kernel(
        const float* __restrict__ Aagg, const float* __restrict__ Hin,
        const float* __restrict__ Wl,   const float* __restrict__ Wr,
        const float* __restrict__ bl,   float* __restrict__ out, int M) {
    __shared__ float As[64][33];     // +1 pad breaks row-bank aliasing
    __shared__ float Ws[32][132];    // +4 pad, keeps 16B alignment for float4
    int tid  = threadIdx.x;
    int tcol = tid & 15;             // 16 col-groups of 8
    int trow = tid >> 4;             // 16 row-groups of 4
    int row0 = blockIdx.x * 64;

    float acc[4][8];
#pragma unroll
    for (int i = 0; i < 4; ++i)
#pragma unroll
        for (int j = 0; j < 8; ++j) acc[i][j] = 0.f;

#pragma unroll
    for (int half = 0; half < 2; ++half) {
        const float* A = half ? Hin : Aagg;
        const float* W = half ? Wr  : Wl;
        for (int kc = 0; kc < 128; kc += 32) {
            // stage A tile 64x32
#pragma unroll
            for (int p = 0; p < 2; ++p) {
                int idx = p * 256 + tid;         // 0..511 float4 slots
                int r   = idx >> 3;
                int k4  = (idx & 7) << 2;
                float4 v = make_float4(0.f, 0.f, 0.f, 0.f);
                int gr = row0 + r;
                if (gr < M) v = *(const float4*)(A + (size_t)gr * D + kc + k4);
                As[r][k4] = v.x; As[r][k4 + 1] = v.y; As[r][k4 + 2] = v.z; As[r][k4 + 3] = v.w;
            }
            // stage W tile 32x128
#pragma unroll
            for (int p = 0; p < 4; ++p) {
                int idx = p * 256 + tid;         // 0..1023 float4 slots
                int k   = idx >> 5;
                int c4  = (idx & 31) << 2;
                float4 v = *(const float4*)(W + (size_t)(kc + k) * D + c4);
                *(float4*)(&Ws[k][c4]) = v;
            }
            __syncthreads();
#pragma unroll 8
            for (int k = 0; k < 32; ++k) {
                float a[4], b[8];
#pragma unroll
                for (int i = 0; i < 4; ++i) a[i] = As[trow * 4 + i][k];
#pragma unroll
                for (int j = 0; j < 8; ++j) b[j] = Ws[k][tcol * 8 + j];
#pragma unroll
                for (int i = 0; i < 4; ++i)
#pragma unroll
                    for (int j = 0; j < 8; ++j) acc[i][j] += a[i] * b[j];
            }
            __syncthreads();
        }
    }
    // epilogue: + bias, relu
#pragma unroll
    for (int i = 0; i < 4; ++i) {
        int gr = row0 + trow * 4 + i;
        if (gr < M) {
#pragma unroll
            for (int j = 0; j < 8; ++j) {
                int c = tcol * 8 + j;
                out[(size_t)gr * D + c] = fmaxf(acc[i][j] + bl[c], 0.f);
            }
        }
    }
}

// ---------------- global max pool + root extraction ----------------

__global__ void pool_kernel(const float* __restrict__ h, const int* __restrict__ batch,
                            float* __restrict__ pooled, int* __restrict__ root, int n) {
    int g = blockIdx.x;
    int f = threadIdx.x;   // 128 threads, one feature each
    // lower_bound(batch, g) and lower_bound(batch, g+1)
    int lo = 0, hi = n;
    while (lo < hi) { int m = (lo + hi) >> 1; if (batch[m] < g) lo = m + 1; else hi = m; }
    int start = lo;
    hi = n;
    while (lo < hi) { int m = (lo + hi) >> 1; if (batch[m] < g + 1) lo = m + 1; else hi = m; }
    int end = lo;
    if (f == 0) root[g] = start;
    float m = -3.4e38f;
    for (int i = start; i < end; ++i) m = fmaxf(m, h[(size_t)i * D + f]);
    pooled[(size_t)g * D + f] = m;
}

// ---------------- MLP head, one block per graph ----------------

__global__ __launch_bounds__(256) void head_kernel(
        const float* __restrict__ pooled, const int* __restrict__ root,
        const float* __restrict__ x,
        const float* __restrict__ W_f1, const float* __restrict__ b_f1,
        const float* __restrict__ W_f2, const float* __restrict__ b_f2,
        const float* __restrict__ W_sm, const float* __restrict__ b_sm,
        const float* __restrict__ W_news, const float* __restrict__ b_news,
        const float* __restrict__ W_cat, const float* __restrict__ b_cat,
        float* __restrict__ out) {
    int g = blockIdx.x;
    int tid = threadIdx.x;   // 256
    __shared__ float p[128], t1[256], t2[128], hs[2], nw[2];
    if (tid < 128) p[tid] = pooled[(size_t)g * D + tid];
    __syncthreads();
    // fc1: 128 -> 256 (W_f1 row-major [128][256], coalesced over tid)
    float a1 = b_f1[tid];
    for (int k = 0; k < 128; ++k) a1 += p[k] * W_f1[k * 256 + tid];
    t1[tid] = fmaxf(a1, 0.f);
    __syncthreads();
    // fc2: 256 -> 128
    if (tid < 128) {
        float a2 = b_f2[tid];
        for (int k = 0; k < 256; ++k) a2 += t1[k] * W_f2[k * 128 + tid];
        t2[tid] = fmaxf(a2, 0.f);
    }
    __syncthreads();
    if (tid < 2) {
        float a3 = b_sm[tid];
        for (int k = 0; k < 128; ++k) a3 += t2[k] * W_sm[k * 2 + tid];
        hs[tid] = fmaxf(a3, 0.f);
        const float* xr = x + (size_t)root[g] * D;
        float a4 = b_news[tid];
        for (int k = 0; k < 128; ++k) a4 += xr[k] * W_news[k * 2 + tid];
        nw[tid] = fmaxf(a4, 0.f);
    }
    __syncthreads();
    if (tid == 0) {
        float o = b_cat[0] + hs[0] * W_cat[0] + hs[1] * W_cat[1]
                           + nw[0] * W_cat[2] + nw[1] * W_cat[3];
        out[g] = 1.0f / (1.0f + __expf(-o));
    }
}

// ---------------- launch ----------------

extern "C" void kernel_launch(void* const* d_in, const int* in_sizes, int n_in,
                              void* d_out, int out_size, void* d_ws, size_t ws_size,
                              hipStream_t stream) {
    const float* x      = (const float*)d_in[0];
    const int*   edge   = (const int*)d_in[1];
    const int*   batch  = (const int*)d_in[2];
    const float* Wl1 = (const float*)d_in[3];
    const float* Wr1 = (const float*)d_in[4];
    const float* bl1 = (const float*)d_in[5];
    const float* Wl2 = (const float*)d_in[6];
    const float* Wr2 = (const float*)d_in[7];
    const float* bl2 = (const float*)d_in[8];
    const float* Wl3 = (const float*)d_in[9];
    const float* Wr3 = (const float*)d_in[10];
    const float* bl3 = (const float*)d_in[11];
    const float* W_f1 = (const float*)d_in[12];
    const float* b_f1 = (const float*)d_in[13];
    const float* W_f2 = (const float*)d_in[14];
    const float* b_f2 = (const float*)d_in[15];
    const float* W_sm = (const float*)d_in[16];
    const float* b_sm = (const float*)d_in[17];
    const float* W_news = (const float*)d_in[18];
    const float* b_news = (const float*)d_in[19];
    const float* W_cat = (const float*)d_in[20];
    const float* b_cat = (const float*)d_in[21];
    float* out = (float*)d_out;

    const int E = in_sizes[1] / 2;
    const int n = in_sizes[2];       // N nodes
    const int B = out_size;          // graphs

    const int* src = edge;
    const int* dst = edge + E;

    // workspace carve-up (256B aligned)
    char* ws = (char*)d_ws;
    size_t off = 0;
    auto carve = [&](size_t bytes) {
        void* pt = ws + off;
        off = (off + bytes + 255) & ~(size_t)255;
        return pt;
    };
    int*   deg     = (int*)carve((size_t)n * 4);
    int*   row_ptr = (int*)carve((size_t)(n + 1) * 4);
    int*   cursor  = (int*)carve((size_t)n * 4);
    float* inv_deg = (float*)carve((size_t)n * 4);
    int*   col     = (int*)carve((size_t)E * 4);
    float* agg     = (float*)carve((size_t)n * D * 4);
    float* hA      = (float*)carve((size_t)n * D * 4);
    float* hB      = (float*)carve((size_t)n * D * 4);
    float* pooled  = (float*)carve((size_t)B * D * 4);
    int*   root    = (int*)carve((size_t)B * 4);
    (void)ws_size;

    // CSR build (once per launch; workspace is re-poisoned every call)
    hipMemsetAsync(deg, 0, (size_t)n * 4, stream);
    deg_kernel<<<(E + 255) / 256, 256, 0, stream>>>(dst, deg, E);
    scan_kernel<<<1, 1024, 0, stream>>>(deg, row_ptr, cursor, inv_deg, n);
    fill_kernel<<<(E + 255) / 256, 256, 0, stream>>>(src, dst, cursor, col, E);

    int agg_blocks = (n * 64 + 255) / 256;
    int mm_blocks  = (n + 63) / 64;

    // layer 1
    agg_kernel<<<agg_blocks, 256, 0, stream>>>(x, row_ptr, col, inv_deg, agg, n);
    sage_mm_kernel<<<mm_blocks, 256, 0, stream>>>(agg, x, Wl1, Wr1, bl1, hA, n);
    // layer 2
    agg_kernel<<<agg_blocks, 256, 0, stream>>>(hA, row_ptr, col, inv_deg, agg, n);
    sage_mm_kernel<<<mm_blocks, 256, 0, stream>>>(agg, hA, Wl2, Wr2, bl2, hB, n);
    // layer 3
    agg_kernel<<<agg_blocks, 256, 0, stream>>>(hB, row_ptr, col, inv_deg, agg, n);
    sage_mm_kernel<<<mm_blocks, 256, 0, stream>>>(agg, hB, Wl3, Wr3, bl3, hA, n);

    // pool + head
    pool_kernel<<<B, 128, 0, stream>>>(hA, batch, pooled, root, n);
    head_kernel<<<B, 256, 0, stream>>>(pooled, root, x,
                                       W_f1, b_f1, W_f2, b_f2, W_sm, b_sm,
                                       W_news, b_news, W_cat, b_cat, out);
}

// Round 2
// 600.253 us; speedup vs baseline: 1.3242x; 1.3242x over previous
//
#include <hip/hip_runtime.h>
#include <hip/hip_bf16.h>
#include <math.h>

#define D 128

// ---------------- CSR build ----------------

__global__ void deg_kernel(const int* __restrict__ dst, int* __restrict__ deg, int E) {
    int e = blockIdx.x * blockDim.x + threadIdx.x;
    if (e < E) atomicAdd(&deg[dst[e]], 1);
}

// phase 1: per-1024-tile sums. grid = ceil(n/1024), 256 threads, 4 elems/thread
__global__ __launch_bounds__(256) void block_sum_kernel(const int* __restrict__ deg,
                                                        int* __restrict__ bsum, int n) {
    __shared__ int red[256];
    int b = blockIdx.x, tid = threadIdx.x;
    int base = b * 1024 + tid * 4;
    int s = 0;
    if (base + 3 < n) {
        int4 v = *(const int4*)(deg + base);
        s = v.x + v.y + v.z + v.w;
    } else {
        for (int i = 0; i < 4; ++i) if (base + i < n) s += deg[base + i];
    }
    red[tid] = s;
    __syncthreads();
    for (int off = 128; off; off >>= 1) {
        if (tid < off) red[tid] += red[tid + off];
        __syncthreads();
    }
    if (tid == 0) bsum[b] = red[0];
}

// phase 2: one wave scans <=64 tile sums in registers -> exclusive offsets in-place
__global__ void bsum_scan_kernel(int* __restrict__ bsum, int nb) {
    int lane = threadIdx.x;   // 64 threads; requires nb <= 64 (n <= 65536)
    int v = (lane < nb) ? bsum[lane] : 0;
    for (int off = 1; off < 64; off <<= 1) {
        int t = __shfl_up(v, off, 64);
        if (lane >= off) v += t;
    }
    int ex = __shfl_up(v, 1, 64);
    if (lane == 0) ex = 0;
    if (lane < nb) bsum[lane] = ex;
}

// phase 3: re-scan each tile, emit row_ptr / cursor / inv_deg
__global__ __launch_bounds__(256) void emit_kernel(const int* __restrict__ deg,
                                                   const int* __restrict__ boff,
                                                   int* __restrict__ row_ptr,
                                                   int* __restrict__ cursor,
                                                   float* __restrict__ inv_deg,
                                                   int n, int E) {
    __shared__ int tsum[256];
    int b = blockIdx.x, tid = threadIdx.x;
    int base = b * 1024 + tid * 4;
    int v[4]; int s = 0;
#pragma unroll
    for (int i = 0; i < 4; ++i) {
        int idx = base + i;
        v[i] = (idx < n) ? deg[idx] : 0;
        s += v[i];
    }
    tsum[tid] = s;
    __syncthreads();
    for (int off = 1; off < 256; off <<= 1) {
        int t = (tid >= off) ? tsum[tid - off] : 0;
        __syncthreads();
        tsum[tid] += t;
        __syncthreads();
    }
    int run = boff[b] + tsum[tid] - s;   // exclusive prefix of this thread's 4 elems
#pragma unroll
    for (int i = 0; i < 4; ++i) {
        int idx = base + i;
        if (idx < n) {
            row_ptr[idx] = run;
            cursor[idx]  = run;
            inv_deg[idx] = 1.0f / (float)((v[i] > 0) ? v[i] : 1);
            run += v[i];
        }
    }
    if (b == 0 && tid == 0) row_ptr[n] = E;
}

__global__ void fill_kernel(const int* __restrict__ src, const int* __restrict__ dst,
                            int* __restrict__ cursor, int* __restrict__ col, int E) {
    int e = blockIdx.x * blockDim.x + threadIdx.x;
    if (e >= E) return;
    int pos = atomicAdd(&cursor[dst[e]], 1);
    col[pos] = src[e];
}

// ---------------- mean aggregation ----------------
// one wave per node; 2 neighbors per iteration (half-wave each, float4/lane),
// combined at the end with shfl_xor(32)

__global__ void agg_kernel(const float* __restrict__ h, const int* __restrict__ row_ptr,
                           const int* __restrict__ col, const float* __restrict__ inv_deg,
                           float* __restrict__ out, int n) {
    int w = (blockIdx.x * blockDim.x + threadIdx.x) >> 6;
    int lane = threadIdx.x & 63;
    if (w >= n) return;
    int s = row_ptr[w], e = row_ptr[w + 1];
    int half = lane >> 5, l32 = lane & 31;
    float4 acc = make_float4(0.f, 0.f, 0.f, 0.f);
    for (int p = s + half; p < e; p += 2) {
        int j = col[p];
        float4 v = ((const float4*)(h + (size_t)j * D))[l32];
        acc.x += v.x; acc.y += v.y; acc.z += v.z; acc.w += v.w;
    }
    acc.x += __shfl_xor(acc.x, 32, 64);
    acc.y += __shfl_xor(acc.y, 32, 64);
    acc.z += __shfl_xor(acc.z, 32, 64);
    acc.w += __shfl_xor(acc.w, 32, 64);
    if (half == 0) {
        float sc = inv_deg[w];
        ((float4*)(out + (size_t)w * D))[l32] =
            make_float4(acc.x * sc, acc.y * sc, acc.z * sc, acc.w * sc);
    }
}

// ---------------- fused dual GEMM: out = relu(Aagg@Wl + Hin@Wr + bl) ----------------

__global__ __launch_bounds__(256) void sage_mm_kernel(
        const float* __restrict__ Aagg, const float* __restrict__ Hin,
        const float* __restrict__ Wl,   const float* __restrict__ Wr,
        const float* __restrict__ bl,   float* __restrict__ out, int M) {
    __shared__ float As[64][33];
    __shared__ float Ws[32][132];
    int tid  = threadIdx.x;
    int tcol = tid & 15;
    int trow = tid >> 4;
    int row0 = blockIdx.x * 64;

    float acc[4][8];
#pragma unroll
    for (int i = 0; i < 4; ++i)
#pragma unroll
        for (int j = 0; j < 8; ++j) acc[i][j] = 0.f;

#pragma unroll
    for (int half = 0; half < 2; ++half) {
        const float* A = half ? Hin : Aagg;
        const float* W = half ? Wr  : Wl;
        for (int kc = 0; kc < 128; kc += 32) {
#pragma unroll
            for (int p = 0; p < 2; ++p) {
                int idx = p * 256 + tid;
                int r   = idx >> 3;
                int k4  = (idx & 7) << 2;
                float4 v = make_float4(0.f, 0.f, 0.f, 0.f);
                int gr = row0 + r;
                if (gr < M) v = *(const float4*)(A + (size_t)gr * D + kc + k4);
                As[r][k4] = v.x; As[r][k4 + 1] = v.y; As[r][k4 + 2] = v.z; As[r][k4 + 3] = v.w;
            }
#pragma unroll
            for (int p = 0; p < 4; ++p) {
                int idx = p * 256 + tid;
                int k   = idx >> 5;
                int c4  = (idx & 31) << 2;
                float4 v = *(const float4*)(W + (size_t)(kc + k) * D + c4);
                *(float4*)(&Ws[k][c4]) = v;
            }
            __syncthreads();
#pragma unroll 8
            for (int k = 0; k < 32; ++k) {
                float a[4], b[8];
#pragma unroll
                for (int i = 0; i < 4; ++i) a[i] = As[trow * 4 + i][k];
#pragma unroll
                for (int j = 0; j < 8; ++j) b[j] = Ws[k][tcol * 8 + j];
#pragma unroll
                for (int i = 0; i < 4; ++i)
#pragma unroll
                    for (int j = 0; j < 8; ++j) acc[i][j] += a[i] * b[j];
            }
            __syncthreads();
        }
    }
#pragma unroll
    for (int i = 0; i < 4; ++i) {
        int gr = row0 + trow * 4 + i;
        if (gr < M) {
#pragma unroll
            for (int j = 0; j < 8; ++j) {
                int c = tcol * 8 + j;
                out[(size_t)gr * D + c] = fmaxf(acc[i][j] + bl[c], 0.f);
            }
        }
    }
}

// ---------------- global max pool + root extraction ----------------

__global__ void pool_kernel(const float* __restrict__ h, const int* __restrict__ batch,
                            float* __restrict__ pooled, int* __restrict__ root, int n) {
    int g = blockIdx.x;
    int f = threadIdx.x;
    int lo = 0, hi = n;
    while (lo < hi) { int m = (lo + hi) >> 1; if (batch[m] < g) lo = m + 1; else hi = m; }
    int start = lo;
    hi = n;
    while (lo < hi) { int m = (lo + hi) >> 1; if (batch[m] < g + 1) lo = m + 1; else hi = m; }
    int end = lo;
    if (f == 0) root[g] = start;
    float m = -3.4e38f;
    for (int i = start; i < end; ++i) m = fmaxf(m, h[(size_t)i * D + f]);
    pooled[(size_t)g * D + f] = m;
}

// ---------------- MLP head, one block per graph ----------------

__global__ __launch_bounds__(256) void head_kernel(
        const float* __restrict__ pooled, const int* __restrict__ root,
        const float* __restrict__ x,
        const float* __restrict__ W_f1, const float* __restrict__ b_f1,
        const float* __restrict__ W_f2, const float* __restrict__ b_f2,
        const float* __restrict__ W_sm, const float* __restrict__ b_sm,
        const float* __restrict__ W_news, const float* __restrict__ b_news,
        const float* __restrict__ W_cat, const float* __restrict__ b_cat,
        float* __restrict__ out) {
    int g = blockIdx.x;
    int tid = threadIdx.x;
    __shared__ float p[128], t1[256], t2[128], hs[2], nw[2];
    if (tid < 128) p[tid] = pooled[(size_t)g * D + tid];
    __syncthreads();
    float a1 = b_f1[tid];
    for (int k = 0; k < 128; ++k) a1 += p[k] * W_f1[k * 256 + tid];
    t1[tid] = fmaxf(a1, 0.f);
    __syncthreads();
    if (tid < 128) {
        float a2 = b_f2[tid];
        for (int k = 0; k < 256; ++k) a2 += t1[k] * W_f2[k * 128 + tid];
        t2[tid] = fmaxf(a2, 0.f);
    }
    __syncthreads();
    if (tid < 2) {
        float a3 = b_sm[tid];
        for (int k = 0; k < 128; ++k) a3 += t2[k] * W_sm[k * 2 + tid];
        hs[tid] = fmaxf(a3, 0.f);
        const float* xr = x + (size_t)root[g] * D;
        float a4 = b_news[tid];
        for (int k = 0; k < 128; ++k) a4 += xr[k] * W_news[k * 2 + tid];
        nw[tid] = fmaxf(a4, 0.f);
    }
    __syncthreads();
    if (tid == 0) {
        float o = b_cat[0] + hs[0] * W_cat[0] + hs[1] * W_cat[1]
                           + nw[0] * W_cat[2] + nw[1] * W_cat[3];
        out[g] = 1.0f / (1.0f + __expf(-o));
    }
}

// ---------------- launch ----------------

extern "C" void kernel_launch(void* const* d_in, const int* in_sizes, int n_in,
                              void* d_out, int out_size, void* d_ws, size_t ws_size,
                              hipStream_t stream) {
    const float* x      = (const float*)d_in[0];
    const int*   edge   = (const int*)d_in[1];
    const int*   batch  = (const int*)d_in[2];
    const float* Wl1 = (const float*)d_in[3];
    const float* Wr1 = (const float*)d_in[4];
    const float* bl1 = (const float*)d_in[5];
    const float* Wl2 = (const float*)d_in[6];
    const float* Wr2 = (const float*)d_in[7];
    const float* bl2 = (const float*)d_in[8];
    const float* Wl3 = (const float*)d_in[9];
    const float* Wr3 = (const float*)d_in[10];
    const float* bl3 = (const float*)d_in[11];
    const float* W_f1 = (const float*)d_in[12];
    const float* b_f1 = (const float*)d_in[13];
    const float* W_f2 = (const float*)d_in[14];
    const float* b_f2 = (const float*)d_in[15];
    const float* W_sm = (const float*)d_in[16];
    const float* b_sm = (const float*)d_in[17];
    const float* W_news = (const float*)d_in[18];
    const float* b_news = (const float*)d_in[19];
    const float* W_cat = (const float*)d_in[20];
    const float* b_cat = (const float*)d_in[21];
    float* out = (float*)d_out;

    const int E = in_sizes[1] / 2;
    const int n = in_sizes[2];
    const int B = out_size;

    const int* src = edge;
    const int* dst = edge + E;

    char* ws = (char*)d_ws;
    size_t off = 0;
    auto carve = [&](size_t bytes) {
        void* pt = ws + off;
        off = (off + bytes + 255) & ~(size_t)255;
        return pt;
    };
    int*   deg     = (int*)carve((size_t)n * 4);
    int*   row_ptr = (int*)carve((size_t)(n + 1) * 4);
    int*   cursor  = (int*)carve((size_t)n * 4);
    float* inv_deg = (float*)carve((size_t)n * 4);
    int*   col     = (int*)carve((size_t)E * 4);
    int*   bsum    = (int*)carve((size_t)256 * 4);
    float* agg     = (float*)carve((size_t)n * D * 4);
    float* hA      = (float*)carve((size_t)n * D * 4);
    float* hB      = (float*)carve((size_t)n * D * 4);
    float* pooled  = (float*)carve((size_t)B * D * 4);
    int*   root    = (int*)carve((size_t)B * 4);
    (void)ws_size;

    // CSR build
    int nb = (n + 1023) / 1024;   // 49 for n=50000; bsum_scan handles nb<=64
    hipMemsetAsync(deg, 0, (size_t)n * 4, stream);
    deg_kernel<<<(E + 255) / 256, 256, 0, stream>>>(dst, deg, E);
    block_sum_kernel<<<nb, 256, 0, stream>>>(deg, bsum, n);
    bsum_scan_kernel<<<1, 64, 0, stream>>>(bsum, nb);
    emit_kernel<<<nb, 256, 0, stream>>>(deg, bsum, row_ptr, cursor, inv_deg, n, E);
    fill_kernel<<<(E + 255) / 256, 256, 0, stream>>>(src, dst, cursor, col, E);

    int agg_blocks = (n * 64 + 255) / 256;
    int mm_blocks  = (n + 63) / 64;

    agg_kernel<<<agg_blocks, 256, 0, stream>>>(x, row_ptr, col, inv_deg, agg, n);
    sage_mm_kernel<<<mm_blocks, 256, 0, stream>>>(agg, x, Wl1, Wr1, bl1, hA, n);
    agg_kernel<<<agg_blocks, 256, 0, stream>>>(hA, row_ptr, col, inv_deg, agg, n);
    sage_mm_kernel<<<mm_blocks, 256, 0, stream>>>(agg, hA, Wl2, Wr2, bl2, hB, n);
    agg_kernel<<<agg_blocks, 256, 0, stream>>>(hB, row_ptr, col, inv_deg, agg, n);
    sage_mm_kernel<<<mm_blocks, 256, 0, stream>>>(agg, hB, Wl3, Wr3, bl3, hA, n);

    pool_kernel<<<B, 128, 0, stream>>>(hA, batch, pooled, root, n);
    head_kernel<<<B, 256, 0, stream>>>(pooled, root, x,
                                       W_f1, b_f1, W_f2, b_f2, W_sm, b_sm,
                                       W_news, b_news, W_cat, b_cat, out);
}

// Round 3
// 393.159 us; speedup vs baseline: 2.0217x; 1.5267x over previous
//
#include <hip/hip_runtime.h>
#include <hip/hip_bf16.h>
#include <math.h>

#define D 128
#define SA 144   // LDS row stride (bf16) for MFMA tiles: 72 dwords % 32 = 8 -> conflict-free

typedef __attribute__((ext_vector_type(8))) short bf16x8;
typedef __attribute__((ext_vector_type(4))) float f32x4;

static __device__ __forceinline__ short f2b(float f) {
    unsigned u = __builtin_bit_cast(unsigned, f);
    unsigned r = (u + 0x7FFFu + ((u >> 16) & 1u)) >> 16;
    return (short)r;
}
static __device__ __forceinline__ float b2f(short b) {
    unsigned u = ((unsigned)(unsigned short)b) << 16;
    return __builtin_bit_cast(float, u);
}

// ---------------- one-time conversions ----------------

// x (N x 128 f32) -> xb (N x 128 bf16), vectorized
__global__ __launch_bounds__(256) void conv_x_kernel(const float* __restrict__ x,
                                                     short* __restrict__ xb, int total4) {
    int idx = blockIdx.x * 256 + threadIdx.x;   // one float4 per thread
    if (idx >= total4) return;
    float4 v = ((const float4*)x)[idx];
    short4 o;
    o.x = f2b(v.x); o.y = f2b(v.y); o.z = f2b(v.z); o.w = f2b(v.w);
    ((short4*)xb)[idx] = o;
}

// 6 weight matrices (128x128 f32, k-major) -> transposed bf16 (n-major)
struct WPack { const float* w[6]; short* o[6]; };
__global__ __launch_bounds__(256) void conv_w_kernel(WPack p) {
    const float* W = p.w[blockIdx.y];
    short* O = p.o[blockIdx.y];
    int idx = blockIdx.x * 256 + threadIdx.x;   // 0..16383
    int k = idx >> 7, nn = idx & 127;
    O[nn * D + k] = f2b(W[k * D + nn]);
}

// ---------------- CSR build ----------------

__global__ void deg_kernel(const int* __restrict__ dst, int* __restrict__ deg, int E) {
    int e = blockIdx.x * blockDim.x + threadIdx.x;
    if (e < E) atomicAdd(&deg[dst[e]], 1);
}

__global__ __launch_bounds__(256) void block_sum_kernel(const int* __restrict__ deg,
                                                        int* __restrict__ bsum, int n) {
    __shared__ int red[256];
    int b = blockIdx.x, tid = threadIdx.x;
    int base = b * 1024 + tid * 4;
    int s = 0;
    if (base + 3 < n) {
        int4 v = *(const int4*)(deg + base);
        s = v.x + v.y + v.z + v.w;
    } else {
        for (int i = 0; i < 4; ++i) if (base + i < n) s += deg[base + i];
    }
    red[tid] = s;
    __syncthreads();
    for (int off = 128; off; off >>= 1) {
        if (tid < off) red[tid] += red[tid + off];
        __syncthreads();
    }
    if (tid == 0) bsum[b] = red[0];
}

__global__ void bsum_scan_kernel(int* __restrict__ bsum, int nb) {
    int lane = threadIdx.x;
    int v = (lane < nb) ? bsum[lane] : 0;
    for (int off = 1; off < 64; off <<= 1) {
        int t = __shfl_up(v, off, 64);
        if (lane >= off) v += t;
    }
    int ex = __shfl_up(v, 1, 64);
    if (lane == 0) ex = 0;
    if (lane < nb) bsum[lane] = ex;
}

__global__ __launch_bounds__(256) void emit_kernel(const int* __restrict__ deg,
                                                   const int* __restrict__ boff,
                                                   int* __restrict__ row_ptr,
                                                   int* __restrict__ cursor,
                                                   float* __restrict__ inv_deg,
                                                   int n, int E) {
    __shared__ int tsum[256];
    int b = blockIdx.x, tid = threadIdx.x;
    int base = b * 1024 + tid * 4;
    int v[4]; int s = 0;
#pragma unroll
    for (int i = 0; i < 4; ++i) {
        int idx = base + i;
        v[i] = (idx < n) ? deg[idx] : 0;
        s += v[i];
    }
    tsum[tid] = s;
    __syncthreads();
    for (int off = 1; off < 256; off <<= 1) {
        int t = (tid >= off) ? tsum[tid - off] : 0;
        __syncthreads();
        tsum[tid] += t;
        __syncthreads();
    }
    int run = boff[b] + tsum[tid] - s;
#pragma unroll
    for (int i = 0; i < 4; ++i) {
        int idx = base + i;
        if (idx < n) {
            row_ptr[idx] = run;
            cursor[idx]  = run;
            inv_deg[idx] = 1.0f / (float)((v[i] > 0) ? v[i] : 1);
            run += v[i];
        }
    }
    if (b == 0 && tid == 0) row_ptr[n] = E;
}

__global__ void fill_kernel(const int* __restrict__ src, const int* __restrict__ dst,
                            int* __restrict__ cursor, int* __restrict__ col, int E) {
    int e = blockIdx.x * blockDim.x + threadIdx.x;
    if (e >= E) return;
    int pos = atomicAdd(&cursor[dst[e]], 1);
    col[pos] = src[e];
}

// ---------------- mean aggregation (bf16 in, bf16 out, f32 accumulate) ----------------
// one wave per node; 4 neighbors/iter: 4 groups of 16 lanes, 16B (8 bf16) per lane

__global__ void agg_kernel(const short* __restrict__ h, const int* __restrict__ row_ptr,
                           const int* __restrict__ col, const float* __restrict__ inv_deg,
                           short* __restrict__ out, int n) {
    int w = (blockIdx.x * blockDim.x + threadIdx.x) >> 6;
    int lane = threadIdx.x & 63;
    if (w >= n) return;
    int s = row_ptr[w], e = row_ptr[w + 1];
    int g = lane >> 4, l16 = lane & 15;
    float acc[8];
#pragma unroll
    for (int q = 0; q < 8; ++q) acc[q] = 0.f;
    for (int p = s + g; p < e; p += 4) {
        int j = col[p];
        bf16x8 v = *(const bf16x8*)(h + (size_t)j * D + l16 * 8);
#pragma unroll
        for (int q = 0; q < 8; ++q) acc[q] += b2f(v[q]);
    }
#pragma unroll
    for (int q = 0; q < 8; ++q) {
        acc[q] += __shfl_xor(acc[q], 16, 64);
        acc[q] += __shfl_xor(acc[q], 32, 64);
    }
    if (g == 0) {
        float sc = inv_deg[w];
        bf16x8 o;
#pragma unroll
        for (int q = 0; q < 8; ++q) o[q] = f2b(acc[q] * sc);
        *(bf16x8*)(out + (size_t)w * D + l16 * 8) = o;
    }
}

// ---------------- fused dual GEMM, bf16 MFMA ----------------
// out = relu(Aagg@Wl + Hin@Wr + bl); block tile 128x128, 4 waves x (2 m-tiles x 8 n-tiles)

__global__ __launch_bounds__(256) void sage_mm_mfma(
        const short* __restrict__ Aagg, const short* __restrict__ Hin,
        const short* __restrict__ WlT,  const short* __restrict__ WrT,
        const float* __restrict__ bl,   short* __restrict__ out, int M) {
    __shared__ short lA[128 * SA];
    __shared__ short lW[128 * SA];
    int tid  = threadIdx.x;
    int wave = tid >> 6, lane = tid & 63;
    int row0 = blockIdx.x * 128;
    int mrow = wave * 32;            // this wave's 32 rows within the tile
    int m16  = lane & 15, quad = lane >> 4;

    f32x4 acc[2][8];
#pragma unroll
    for (int i = 0; i < 2; ++i)
#pragma unroll
        for (int j = 0; j < 8; ++j) acc[i][j] = (f32x4){0.f, 0.f, 0.f, 0.f};

#pragma unroll
    for (int half = 0; half < 2; ++half) {
        const short* A = half ? Hin : Aagg;
        const short* W = half ? WrT : WlT;
        // stage A rows + W^T rows (128 x 128 bf16 each), 16B/lane
#pragma unroll
        for (int it = 0; it < 8; ++it) {
            int idx = it * 256 + tid;        // 0..2047
            int r = idx >> 4, c8 = (idx & 15) << 3;
            bf16x8 va = {0, 0, 0, 0, 0, 0, 0, 0};
            int gr = row0 + r;
            if (gr < M) va = *(const bf16x8*)(A + (size_t)gr * D + c8);
            *(bf16x8*)(&lA[r * SA + c8]) = va;
            bf16x8 vw = *(const bf16x8*)(W + r * D + c8);
            *(bf16x8*)(&lW[r * SA + c8]) = vw;
        }
        __syncthreads();
#pragma unroll
        for (int ks = 0; ks < 4; ++ks) {
            int kb = ks * 32 + quad * 8;
            bf16x8 a0 = *(const bf16x8*)(&lA[(mrow +      m16) * SA + kb]);
            bf16x8 a1 = *(const bf16x8*)(&lA[(mrow + 16 + m16) * SA + kb]);
#pragma unroll
            for (int nt = 0; nt < 8; ++nt) {
                bf16x8 b = *(const bf16x8*)(&lW[(nt * 16 + m16) * SA + kb]);
                acc[0][nt] = __builtin_amdgcn_mfma_f32_16x16x32_bf16(a0, b, acc[0][nt], 0, 0, 0);
                acc[1][nt] = __builtin_amdgcn_mfma_f32_16x16x32_bf16(a1, b, acc[1][nt], 0, 0, 0);
            }
        }
        __syncthreads();
    }
    // epilogue: bias + relu, bf16 store (C/D: row = quad*4+r, col = m16)
#pragma unroll
    for (int mt = 0; mt < 2; ++mt) {
#pragma unroll
        for (int r = 0; r < 4; ++r) {
            int grow = row0 + mrow + mt * 16 + quad * 4 + r;
            if (grow < M) {
#pragma unroll
                for (int nt = 0; nt < 8; ++nt) {
                    int gcol = nt * 16 + m16;
                    float v = acc[mt][nt][r] + bl[gcol];
                    out[(size_t)grow * D + gcol] = f2b(fmaxf(v, 0.f));
                }
            }
        }
    }
}

// ---------------- global max pool + root extraction (bf16 in, f32 out) ----------------

__global__ void pool_kernel(const short* __restrict__ h, const int* __restrict__ batch,
                            float* __restrict__ pooled, int* __restrict__ root, int n) {
    int g = blockIdx.x;
    int f = threadIdx.x;
    int lo = 0, hi = n;
    while (lo < hi) { int m = (lo + hi) >> 1; if (batch[m] < g) lo = m + 1; else hi = m; }
    int start = lo;
    hi = n;
    while (lo < hi) { int m = (lo + hi) >> 1; if (batch[m] < g + 1) lo = m + 1; else hi = m; }
    int end = lo;
    if (f == 0) root[g] = start;
    float m = -3.4e38f;
    for (int i = start; i < end; ++i) m = fmaxf(m, b2f(h[(size_t)i * D + f]));
    pooled[(size_t)g * D + f] = m;
}

// ---------------- MLP head (all f32) ----------------

__global__ __launch_bounds__(256) void head_kernel(
        const float* __restrict__ pooled, const int* __restrict__ root,
        const float* __restrict__ x,
        const float* __restrict__ W_f1, const float* __restrict__ b_f1,
        const float* __restrict__ W_f2, const float* __restrict__ b_f2,
        const float* __restrict__ W_sm, const float* __restrict__ b_sm,
        const float* __restrict__ W_news, const float* __restrict__ b_news,
        const float* __restrict__ W_cat, const float* __restrict__ b_cat,
        float* __restrict__ out) {
    int g = blockIdx.x;
    int tid = threadIdx.x;
    __shared__ float p[128], t1[256], t2[128], hs[2], nw[2];
    if (tid < 128) p[tid] = pooled[(size_t)g * D + tid];
    __syncthreads();
    float a1 = b_f1[tid];
    for (int k = 0; k < 128; ++k) a1 += p[k] * W_f1[k * 256 + tid];
    t1[tid] = fmaxf(a1, 0.f);
    __syncthreads();
    if (tid < 128) {
        float a2 = b_f2[tid];
        for (int k = 0; k < 256; ++k) a2 += t1[k] * W_f2[k * 128 + tid];
        t2[tid] = fmaxf(a2, 0.f);
    }
    __syncthreads();
    if (tid < 2) {
        float a3 = b_sm[tid];
        for (int k = 0; k < 128; ++k) a3 += t2[k] * W_sm[k * 2 + tid];
        hs[tid] = fmaxf(a3, 0.f);
        const float* xr = x + (size_t)root[g] * D;
        float a4 = b_news[tid];
        for (int k = 0; k < 128; ++k) a4 += xr[k] * W_news[k * 2 + tid];
        nw[tid] = fmaxf(a4, 0.f);
    }
    __syncthreads();
    if (tid == 0) {
        float o = b_cat[0] + hs[0] * W_cat[0] + hs[1] * W_cat[1]
                           + nw[0] * W_cat[2] + nw[1] * W_cat[3];
        out[g] = 1.0f / (1.0f + __expf(-o));
    }
}

// ---------------- launch ----------------

extern "C" void kernel_launch(void* const* d_in, const int* in_sizes, int n_in,
                              void* d_out, int out_size, void* d_ws, size_t ws_size,
                              hipStream_t stream) {
    const float* x      = (const float*)d_in[0];
    const int*   edge   = (const int*)d_in[1];
    const int*   batch  = (const int*)d_in[2];
    const float* Wl1 = (const float*)d_in[3];
    const float* Wr1 = (const float*)d_in[4];
    const float* bl1 = (const float*)d_in[5];
    const float* Wl2 = (const float*)d_in[6];
    const float* Wr2 = (const float*)d_in[7];
    const float* bl2 = (const float*)d_in[8];
    const float* Wl3 = (const float*)d_in[9];
    const float* Wr3 = (const float*)d_in[10];
    const float* bl3 = (const float*)d_in[11];
    const float* W_f1 = (const float*)d_in[12];
    const float* b_f1 = (const float*)d_in[13];
    const float* W_f2 = (const float*)d_in[14];
    const float* b_f2 = (const float*)d_in[15];
    const float* W_sm = (const float*)d_in[16];
    const float* b_sm = (const float*)d_in[17];
    const float* W_news = (const float*)d_in[18];
    const float* b_news = (const float*)d_in[19];
    const float* W_cat = (const float*)d_in[20];
    const float* b_cat = (const float*)d_in[21];
    float* out = (float*)d_out;

    const int E = in_sizes[1] / 2;
    const int n = in_sizes[2];
    const int B = out_size;

    const int* src = edge;
    const int* dst = edge + E;

    char* ws = (char*)d_ws;
    size_t off = 0;
    auto carve = [&](size_t bytes) {
        void* pt = ws + off;
        off = (off + bytes + 255) & ~(size_t)255;
        return pt;
    };
    int*   deg     = (int*)carve((size_t)n * 4);
    int*   row_ptr = (int*)carve((size_t)(n + 1) * 4);
    int*   cursor  = (int*)carve((size_t)n * 4);
    float* inv_deg = (float*)carve((size_t)n * 4);
    int*   col     = (int*)carve((size_t)E * 4);
    int*   bsum    = (int*)carve((size_t)256 * 4);
    short* xb      = (short*)carve((size_t)n * D * 2);
    short* aggb    = (short*)carve((size_t)n * D * 2);
    short* hA      = (short*)carve((size_t)n * D * 2);
    short* hB      = (short*)carve((size_t)n * D * 2);
    short* Wt[6];
    for (int i = 0; i < 6; ++i) Wt[i] = (short*)carve((size_t)D * D * 2);
    float* pooled  = (float*)carve((size_t)B * D * 4);
    int*   root    = (int*)carve((size_t)B * 4);
    (void)ws_size;

    // one-time conversions
    int total4 = n * D / 4;
    conv_x_kernel<<<(total4 + 255) / 256, 256, 0, stream>>>(x, xb, total4);
    WPack wp;
    wp.w[0] = Wl1; wp.w[1] = Wr1; wp.w[2] = Wl2; wp.w[3] = Wr2; wp.w[4] = Wl3; wp.w[5] = Wr3;
    for (int i = 0; i < 6; ++i) wp.o[i] = Wt[i];
    conv_w_kernel<<<dim3(64, 6), 256, 0, stream>>>(wp);

    // CSR build
    int nb = (n + 1023) / 1024;
    hipMemsetAsync(deg, 0, (size_t)n * 4, stream);
    deg_kernel<<<(E + 255) / 256, 256, 0, stream>>>(dst, deg, E);
    block_sum_kernel<<<nb, 256, 0, stream>>>(deg, bsum, n);
    bsum_scan_kernel<<<1, 64, 0, stream>>>(bsum, nb);
    emit_kernel<<<nb, 256, 0, stream>>>(deg, bsum, row_ptr, cursor, inv_deg, n, E);
    fill_kernel<<<(E + 255) / 256, 256, 0, stream>>>(src, dst, cursor, col, E);

    int agg_blocks = (n * 64 + 255) / 256;
    int mm_blocks  = (n + 127) / 128;

    agg_kernel<<<agg_blocks, 256, 0, stream>>>(xb, row_ptr, col, inv_deg, aggb, n);
    sage_mm_mfma<<<mm_blocks, 256, 0, stream>>>(aggb, xb, Wt[0], Wt[1], bl1, hA, n);
    agg_kernel<<<agg_blocks, 256, 0, stream>>>(hA, row_ptr, col, inv_deg, aggb, n);
    sage_mm_mfma<<<mm_blocks, 256, 0, stream>>>(aggb, hA, Wt[2], Wt[3], bl2, hB, n);
    agg_kernel<<<agg_blocks, 256, 0, stream>>>(hB, row_ptr, col, inv_deg, aggb, n);
    sage_mm_mfma<<<mm_blocks, 256, 0, stream>>>(aggb, hB, Wt[4], Wt[5], bl3, hA, n);

    pool_kernel<<<B, 128, 0, stream>>>(hA, batch, pooled, root, n);
    head_kernel<<<B, 256, 0, stream>>>(pooled, root, x,
                                       W_f1, b_f1, W_f2, b_f2, W_sm, b_sm,
                                       W_news, b_news, W_cat, b_cat, out);
}

// Round 4
// 372.961 us; speedup vs baseline: 2.1312x; 1.0542x over previous
//
#include <hip/hip_runtime.h>
#include <hip/hip_bf16.h>
#include <math.h>

#define D 128
#define SA 144   // LDS row stride (bf16) for MFMA tiles: 72 dwords % 32 = 8 -> conflict-free

typedef __attribute__((ext_vector_type(8))) short bf16x8;
typedef __attribute__((ext_vector_type(4))) float f32x4;

static __device__ __forceinline__ short f2b(float f) {
    unsigned u = __builtin_bit_cast(unsigned, f);
    unsigned r = (u + 0x7FFFu + ((u >> 16) & 1u)) >> 16;
    return (short)r;
}
static __device__ __forceinline__ float b2f(short b) {
    unsigned u = ((unsigned)(unsigned short)b) << 16;
    return __builtin_bit_cast(float, u);
}

// ---------------- one-time conversions ----------------

__global__ __launch_bounds__(256) void conv_x_kernel(const float* __restrict__ x,
                                                     short* __restrict__ xb, int total4) {
    int idx = blockIdx.x * 256 + threadIdx.x;
    if (idx >= total4) return;
    float4 v = ((const float4*)x)[idx];
    short4 o;
    o.x = f2b(v.x); o.y = f2b(v.y); o.z = f2b(v.z); o.w = f2b(v.w);
    ((short4*)xb)[idx] = o;
}

struct WPack { const float* w[6]; short* o[6]; };
__global__ __launch_bounds__(256) void conv_w_kernel(WPack p) {
    const float* W = p.w[blockIdx.y];
    short* O = p.o[blockIdx.y];
    int idx = blockIdx.x * 256 + threadIdx.x;
    int k = idx >> 7, nn = idx & 127;
    O[nn * D + k] = f2b(W[k * D + nn]);
}

// ---------------- CSR build ----------------

__global__ void deg_kernel(const int* __restrict__ dst, int* __restrict__ deg, int E) {
    int e = blockIdx.x * blockDim.x + threadIdx.x;
    if (e < E) atomicAdd(&deg[dst[e]], 1);
}

__global__ __launch_bounds__(256) void block_sum_kernel(const int* __restrict__ deg,
                                                        int* __restrict__ bsum, int n) {
    __shared__ int red[256];
    int b = blockIdx.x, tid = threadIdx.x;
    int base = b * 1024 + tid * 4;
    int s = 0;
    if (base + 3 < n) {
        int4 v = *(const int4*)(deg + base);
        s = v.x + v.y + v.z + v.w;
    } else {
        for (int i = 0; i < 4; ++i) if (base + i < n) s += deg[base + i];
    }
    red[tid] = s;
    __syncthreads();
    for (int off = 128; off; off >>= 1) {
        if (tid < off) red[tid] += red[tid + off];
        __syncthreads();
    }
    if (tid == 0) bsum[b] = red[0];
}

__global__ void bsum_scan_kernel(int* __restrict__ bsum, int nb) {
    int lane = threadIdx.x;
    int v = (lane < nb) ? bsum[lane] : 0;
    for (int off = 1; off < 64; off <<= 1) {
        int t = __shfl_up(v, off, 64);
        if (lane >= off) v += t;
    }
    int ex = __shfl_up(v, 1, 64);
    if (lane == 0) ex = 0;
    if (lane < nb) bsum[lane] = ex;
}

// emit row_ptr / inv_deg, plus gcursor[b] = row_ptr[b*128] (bucket bases for binning)
__global__ __launch_bounds__(256) void emit_kernel(const int* __restrict__ deg,
                                                   const int* __restrict__ boff,
                                                   int* __restrict__ row_ptr,
                                                   float* __restrict__ inv_deg,
                                                   int* __restrict__ gcursor,
                                                   int n, int E) {
    __shared__ int tsum[256];
    int b = blockIdx.x, tid = threadIdx.x;
    int base = b * 1024 + tid * 4;
    int v[4]; int s = 0;
#pragma unroll
    for (int i = 0; i < 4; ++i) {
        int idx = base + i;
        v[i] = (idx < n) ? deg[idx] : 0;
        s += v[i];
    }
    tsum[tid] = s;
    __syncthreads();
    for (int off = 1; off < 256; off <<= 1) {
        int t = (tid >= off) ? tsum[tid - off] : 0;
        __syncthreads();
        tsum[tid] += t;
        __syncthreads();
    }
    int run = boff[b] + tsum[tid] - s;
#pragma unroll
    for (int i = 0; i < 4; ++i) {
        int idx = base + i;
        if (idx < n) {
            row_ptr[idx] = run;
            inv_deg[idx] = 1.0f / (float)((v[i] > 0) ? v[i] : 1);
            if ((idx & 127) == 0) gcursor[idx >> 7] = run;
            run += v[i];
        }
    }
    if (b == 0 && tid == 0) row_ptr[n] = E;
}

// ---------------- bucketed edge placement ----------------
// pass 1: bin edges into bucket-contiguous (src,dst) runs. 4096 edges/block.

#define EPB 4096
__global__ __launch_bounds__(256) void bin_kernel(const int* __restrict__ src,
                                                  const int* __restrict__ dst,
                                                  int* __restrict__ gcursor,
                                                  int2* __restrict__ binned, int E) {
    __shared__ int hist[512];
    __shared__ int base[512];
    int tid = threadIdx.x;
    int e0 = blockIdx.x * EPB;
    hist[tid] = 0; hist[tid + 256] = 0;
    __syncthreads();
    int sv[16], dv[16], bv[16];
#pragma unroll
    for (int i = 0; i < 16; ++i) {
        int e = e0 + i * 256 + tid;
        if (e < E) {
            sv[i] = src[e]; dv[i] = dst[e];
            bv[i] = dv[i] >> 7;
            atomicAdd(&hist[bv[i]], 1);
        } else bv[i] = -1;
    }
    __syncthreads();
    // reserve global space per bucket; reset hist for reuse as local cursor
    {
        int c0 = hist[tid];
        base[tid] = c0 ? atomicAdd(&gcursor[tid], c0) : 0;
        hist[tid] = 0;
        int c1 = hist[tid + 256];
        base[tid + 256] = c1 ? atomicAdd(&gcursor[tid + 256], c1) : 0;
        hist[tid + 256] = 0;
    }
    __syncthreads();
#pragma unroll
    for (int i = 0; i < 16; ++i) {
        if (bv[i] >= 0) {
            int off = atomicAdd(&hist[bv[i]], 1);
            binned[base[bv[i]] + off] = make_int2(sv[i], dv[i]);
        }
    }
}

// pass 2: one block per bucket; place srcs at exact CSR positions (dense 8KB col region)
__global__ __launch_bounds__(256) void place_kernel(const int2* __restrict__ binned,
                                                    const int* __restrict__ row_ptr,
                                                    int* __restrict__ col, int n) {
    __shared__ int cur[128];
    int b = blockIdx.x, tid = threadIdx.x;
    int node0 = b << 7;
    if (tid < 128) {
        int nd = node0 + tid;
        cur[tid] = (nd < n) ? row_ptr[nd] : 0;
    }
    int node1 = node0 + 128; if (node1 > n) node1 = n;
    int start = row_ptr[node0];
    int end   = row_ptr[node1];
    __syncthreads();
    for (int i = start + tid; i < end; i += 256) {
        int2 e = binned[i];
        int pos = atomicAdd(&cur[e.y & 127], 1);
        col[pos] = e.x;
    }
}

// ---------------- mean aggregation (bf16 in/out, f32 accumulate) ----------------

__global__ void agg_kernel(const short* __restrict__ h, const int* __restrict__ row_ptr,
                           const int* __restrict__ col, const float* __restrict__ inv_deg,
                           short* __restrict__ out, int n) {
    int w = (blockIdx.x * blockDim.x + threadIdx.x) >> 6;
    int lane = threadIdx.x & 63;
    if (w >= n) return;
    int s = row_ptr[w], e = row_ptr[w + 1];
    int g = lane >> 4, l16 = lane & 15;
    float acc[8];
#pragma unroll
    for (int q = 0; q < 8; ++q) acc[q] = 0.f;
    for (int p = s + g; p < e; p += 4) {
        int j = col[p];
        bf16x8 v = *(const bf16x8*)(h + (size_t)j * D + l16 * 8);
#pragma unroll
        for (int q = 0; q < 8; ++q) acc[q] += b2f(v[q]);
    }
#pragma unroll
    for (int q = 0; q < 8; ++q) {
        acc[q] += __shfl_xor(acc[q], 16, 64);
        acc[q] += __shfl_xor(acc[q], 32, 64);
    }
    if (g == 0) {
        float sc = inv_deg[w];
        bf16x8 o;
#pragma unroll
        for (int q = 0; q < 8; ++q) o[q] = f2b(acc[q] * sc);
        *(bf16x8*)(out + (size_t)w * D + l16 * 8) = o;
    }
}

// ---------------- fused dual GEMM, bf16 MFMA ----------------

__global__ __launch_bounds__(256) void sage_mm_mfma(
        const short* __restrict__ Aagg, const short* __restrict__ Hin,
        const short* __restrict__ WlT,  const short* __restrict__ WrT,
        const float* __restrict__ bl,   short* __restrict__ out, int M) {
    __shared__ short lA[128 * SA];
    __shared__ short lW[128 * SA];
    int tid  = threadIdx.x;
    int wave = tid >> 6, lane = tid & 63;
    int row0 = blockIdx.x * 128;
    int mrow = wave * 32;
    int m16  = lane & 15, quad = lane >> 4;

    f32x4 acc[2][8];
#pragma unroll
    for (int i = 0; i < 2; ++i)
#pragma unroll
        for (int j = 0; j < 8; ++j) acc[i][j] = (f32x4){0.f, 0.f, 0.f, 0.f};

#pragma unroll
    for (int half = 0; half < 2; ++half) {
        const short* A = half ? Hin : Aagg;
        const short* W = half ? WrT : WlT;
#pragma unroll
        for (int it = 0; it < 8; ++it) {
            int idx = it * 256 + tid;
            int r = idx >> 4, c8 = (idx & 15) << 3;
            bf16x8 va = {0, 0, 0, 0, 0, 0, 0, 0};
            int gr = row0 + r;
            if (gr < M) va = *(const bf16x8*)(A + (size_t)gr * D + c8);
            *(bf16x8*)(&lA[r * SA + c8]) = va;
            bf16x8 vw = *(const bf16x8*)(W + r * D + c8);
            *(bf16x8*)(&lW[r * SA + c8]) = vw;
        }
        __syncthreads();
#pragma unroll
        for (int ks = 0; ks < 4; ++ks) {
            int kb = ks * 32 + quad * 8;
            bf16x8 a0 = *(const bf16x8*)(&lA[(mrow +      m16) * SA + kb]);
            bf16x8 a1 = *(const bf16x8*)(&lA[(mrow + 16 + m16) * SA + kb]);
#pragma unroll
            for (int nt = 0; nt < 8; ++nt) {
                bf16x8 b = *(const bf16x8*)(&lW[(nt * 16 + m16) * SA + kb]);
                acc[0][nt] = __builtin_amdgcn_mfma_f32_16x16x32_bf16(a0, b, acc[0][nt], 0, 0, 0);
                acc[1][nt] = __builtin_amdgcn_mfma_f32_16x16x32_bf16(a1, b, acc[1][nt], 0, 0, 0);
            }
        }
        __syncthreads();
    }
#pragma unroll
    for (int mt = 0; mt < 2; ++mt) {
#pragma unroll
        for (int r = 0; r < 4; ++r) {
            int grow = row0 + mrow + mt * 16 + quad * 4 + r;
            if (grow < M) {
#pragma unroll
                for (int nt = 0; nt < 8; ++nt) {
                    int gcol = nt * 16 + m16;
                    float v = acc[mt][nt][r] + bl[gcol];
                    out[(size_t)grow * D + gcol] = f2b(fmaxf(v, 0.f));
                }
            }
        }
    }
}

// ---------------- global max pool + root extraction ----------------

__global__ void pool_kernel(const short* __restrict__ h, const int* __restrict__ batch,
                            float* __restrict__ pooled, int* __restrict__ root, int n) {
    int g = blockIdx.x;
    int f = threadIdx.x;
    int lo = 0, hi = n;
    while (lo < hi) { int m = (lo + hi) >> 1; if (batch[m] < g) lo = m + 1; else hi = m; }
    int start = lo;
    hi = n;
    while (lo < hi) { int m = (lo + hi) >> 1; if (batch[m] < g + 1) lo = m + 1; else hi = m; }
    int end = lo;
    if (f == 0) root[g] = start;
    float m = -3.4e38f;
    for (int i = start; i < end; ++i) m = fmaxf(m, b2f(h[(size_t)i * D + f]));
    pooled[(size_t)g * D + f] = m;
}

// ---------------- MLP head (all f32) ----------------

__global__ __launch_bounds__(256) void head_kernel(
        const float* __restrict__ pooled, const int* __restrict__ root,
        const float* __restrict__ x,
        const float* __restrict__ W_f1, const float* __restrict__ b_f1,
        const float* __restrict__ W_f2, const float* __restrict__ b_f2,
        const float* __restrict__ W_sm, const float* __restrict__ b_sm,
        const float* __restrict__ W_news, const float* __restrict__ b_news,
        const float* __restrict__ W_cat, const float* __restrict__ b_cat,
        float* __restrict__ out) {
    int g = blockIdx.x;
    int tid = threadIdx.x;
    __shared__ float p[128], t1[256], t2[128], hs[2], nw[2];
    if (tid < 128) p[tid] = pooled[(size_t)g * D + tid];
    __syncthreads();
    float a1 = b_f1[tid];
    for (int k = 0; k < 128; ++k) a1 += p[k] * W_f1[k * 256 + tid];
    t1[tid] = fmaxf(a1, 0.f);
    __syncthreads();
    if (tid < 128) {
        float a2 = b_f2[tid];
        for (int k = 0; k < 256; ++k) a2 += t1[k] * W_f2[k * 128 + tid];
        t2[tid] = fmaxf(a2, 0.f);
    }
    __syncthreads();
    if (tid < 2) {
        float a3 = b_sm[tid];
        for (int k = 0; k < 128; ++k) a3 += t2[k] * W_sm[k * 2 + tid];
        hs[tid] = fmaxf(a3, 0.f);
        const float* xr = x + (size_t)root[g] * D;
        float a4 = b_news[tid];
        for (int k = 0; k < 128; ++k) a4 += xr[k] * W_news[k * 2 + tid];
        nw[tid] = fmaxf(a4, 0.f);
    }
    __syncthreads();
    if (tid == 0) {
        float o = b_cat[0] + hs[0] * W_cat[0] + hs[1] * W_cat[1]
                           + nw[0] * W_cat[2] + nw[1] * W_cat[3];
        out[g] = 1.0f / (1.0f + __expf(-o));
    }
}

// ---------------- launch ----------------

extern "C" void kernel_launch(void* const* d_in, const int* in_sizes, int n_in,
                              void* d_out, int out_size, void* d_ws, size_t ws_size,
                              hipStream_t stream) {
    const float* x      = (const float*)d_in[0];
    const int*   edge   = (const int*)d_in[1];
    const int*   batch  = (const int*)d_in[2];
    const float* Wl1 = (const float*)d_in[3];
    const float* Wr1 = (const float*)d_in[4];
    const float* bl1 = (const float*)d_in[5];
    const float* Wl2 = (const float*)d_in[6];
    const float* Wr2 = (const float*)d_in[7];
    const float* bl2 = (const float*)d_in[8];
    const float* Wl3 = (const float*)d_in[9];
    const float* Wr3 = (const float*)d_in[10];
    const float* bl3 = (const float*)d_in[11];
    const float* W_f1 = (const float*)d_in[12];
    const float* b_f1 = (const float*)d_in[13];
    const float* W_f2 = (const float*)d_in[14];
    const float* b_f2 = (const float*)d_in[15];
    const float* W_sm = (const float*)d_in[16];
    const float* b_sm = (const float*)d_in[17];
    const float* W_news = (const float*)d_in[18];
    const float* b_news = (const float*)d_in[19];
    const float* W_cat = (const float*)d_in[20];
    const float* b_cat = (const float*)d_in[21];
    float* out = (float*)d_out;

    const int E = in_sizes[1] / 2;
    const int n = in_sizes[2];
    const int B = out_size;

    const int* src = edge;
    const int* dst = edge + E;

    char* ws = (char*)d_ws;
    size_t off = 0;
    auto carve = [&](size_t bytes) {
        void* pt = ws + off;
        off = (off + bytes + 255) & ~(size_t)255;
        return pt;
    };
    int*   deg     = (int*)carve((size_t)n * 4);
    int*   row_ptr = (int*)carve((size_t)(n + 1) * 4);
    float* inv_deg = (float*)carve((size_t)n * 4);
    int*   col     = (int*)carve((size_t)E * 4);
    int*   bsum    = (int*)carve((size_t)256 * 4);
    int*   gcursor = (int*)carve((size_t)512 * 4);
    int2*  binned  = (int2*)carve((size_t)E * 8);
    short* xb      = (short*)carve((size_t)n * D * 2);
    short* aggb    = (short*)carve((size_t)n * D * 2);
    short* hA      = (short*)carve((size_t)n * D * 2);
    short* hB      = (short*)carve((size_t)n * D * 2);
    short* Wt[6];
    for (int i = 0; i < 6; ++i) Wt[i] = (short*)carve((size_t)D * D * 2);
    float* pooled  = (float*)carve((size_t)B * D * 4);
    int*   root    = (int*)carve((size_t)B * 4);
    (void)ws_size;

    // one-time conversions
    int total4 = n * D / 4;
    conv_x_kernel<<<(total4 + 255) / 256, 256, 0, stream>>>(x, xb, total4);
    WPack wp;
    wp.w[0] = Wl1; wp.w[1] = Wr1; wp.w[2] = Wl2; wp.w[3] = Wr2; wp.w[4] = Wl3; wp.w[5] = Wr3;
    for (int i = 0; i < 6; ++i) wp.o[i] = Wt[i];
    conv_w_kernel<<<dim3(64, 6), 256, 0, stream>>>(wp);

    // CSR build
    int nb = (n + 1023) / 1024;      // <=64 (bsum_scan limit)
    int NB = (n + 127) / 128;        // buckets, <=512 (bin hist limit)
    hipMemsetAsync(deg, 0, (size_t)n * 4, stream);
    deg_kernel<<<(E + 255) / 256, 256, 0, stream>>>(dst, deg, E);
    block_sum_kernel<<<nb, 256, 0, stream>>>(deg, bsum, n);
    bsum_scan_kernel<<<1, 64, 0, stream>>>(bsum, nb);
    emit_kernel<<<nb, 256, 0, stream>>>(deg, bsum, row_ptr, inv_deg, gcursor, n, E);
    bin_kernel<<<(E + EPB - 1) / EPB, 256, 0, stream>>>(src, dst, gcursor, binned, E);
    place_kernel<<<NB, 256, 0, stream>>>(binned, row_ptr, col, n);

    int agg_blocks = (n * 64 + 255) / 256;
    int mm_blocks  = (n + 127) / 128;

    agg_kernel<<<agg_blocks, 256, 0, stream>>>(xb, row_ptr, col, inv_deg, aggb, n);
    sage_mm_mfma<<<mm_blocks, 256, 0, stream>>>(aggb, xb, Wt[0], Wt[1], bl1, hA, n);
    agg_kernel<<<agg_blocks, 256, 0, stream>>>(hA, row_ptr, col, inv_deg, aggb, n);
    sage_mm_mfma<<<mm_blocks, 256, 0, stream>>>(aggb, hA, Wt[2], Wt[3], bl2, hB, n);
    agg_kernel<<<agg_blocks, 256, 0, stream>>>(hB, row_ptr, col, inv_deg, aggb, n);
    sage_mm_mfma<<<mm_blocks, 256, 0, stream>>>(aggb, hB, Wt[4], Wt[5], bl3, hA, n);

    pool_kernel<<<B, 128, 0, stream>>>(hA, batch, pooled, root, n);
    head_kernel<<<B, 256, 0, stream>>>(pooled, root, x,
                                       W_f1, b_f1, W_f2, b_f2, W_sm, b_sm,
                                       W_news, b_news, W_cat, b_cat, out);
}

// Round 5
// 316.194 us; speedup vs baseline: 2.5138x; 1.1795x over previous
//
#include <hip/hip_runtime.h>
#include <hip/hip_bf16.h>
#include <math.h>

#define D 128
#define SA 144   // LDS row stride (bf16) for MFMA tiles: 72 dwords % 32 = 8 -> conflict-free

typedef __attribute__((ext_vector_type(8))) short bf16x8;
typedef __attribute__((ext_vector_type(4))) float f32x4;

static __device__ __forceinline__ short f2b(float f) {
    unsigned u = __builtin_bit_cast(unsigned, f);
    unsigned r = (u + 0x7FFFu + ((u >> 16) & 1u)) >> 16;
    return (short)r;
}
static __device__ __forceinline__ float b2f(short b) {
    unsigned u = ((unsigned)(unsigned short)b) << 16;
    return __builtin_bit_cast(float, u);
}

// ---------------- prep: conv_x + conv_w + bucket histogram, one launch ----------------

struct PrepArgs {
    const float* x; short* xb; int total4; int xb_blocks;
    const float* w[6]; short* wo[6]; int w_blocks;
    const int* dst; int* bcnt; int E;                 // histogram of dst>>7 into 512 buckets
};

__global__ __launch_bounds__(256) void prep_kernel(PrepArgs a) {
    int bid = blockIdx.x, tid = threadIdx.x;
    if (bid < a.xb_blocks) {
        int idx = bid * 256 + tid;
        if (idx < a.total4) {
            float4 v = ((const float4*)a.x)[idx];
            short4 o;
            o.x = f2b(v.x); o.y = f2b(v.y); o.z = f2b(v.z); o.w = f2b(v.w);
            ((short4*)a.xb)[idx] = o;
        }
        return;
    }
    if (bid < a.xb_blocks + a.w_blocks) {
        int idx4 = (bid - a.xb_blocks) * 256 + tid;   // 4 elems/thread, exact fit
        int base = idx4 * 4;
        int m = base >> 14;            // 16384 elems per matrix
        int i = base & 16383;
        const float* W = a.w[m];
        short* O = a.wo[m];
        int k = i >> 7, nn = i & 127;
        float4 v = *(const float4*)(W + k * D + nn);
        O[(nn + 0) * D + k] = f2b(v.x);
        O[(nn + 1) * D + k] = f2b(v.y);
        O[(nn + 2) * D + k] = f2b(v.z);
        O[(nn + 3) * D + k] = f2b(v.w);
        return;
    }
    // bucket histogram: 4096 edges/block, LDS-first
    __shared__ int hist[512];
    hist[tid] = 0; hist[tid + 256] = 0;
    __syncthreads();
    int e0 = (bid - a.xb_blocks - a.w_blocks) * 4096;
#pragma unroll
    for (int i = 0; i < 16; ++i) {
        int e = e0 + i * 256 + tid;
        if (e < a.E) atomicAdd(&hist[a.dst[e] >> 7], 1);
    }
    __syncthreads();
    int c = hist[tid];       if (c) atomicAdd(&a.bcnt[tid], c);
    c = hist[tid + 256];     if (c) atomicAdd(&a.bcnt[tid + 256], c);
}

// ---------------- scan of 512 bucket counts (one block) ----------------
// gbase[0..512] exclusive prefix (gbase[512]=E); gcursor = working copy for bin

__global__ __launch_bounds__(256) void scan512_kernel(const int* __restrict__ bcnt,
                                                      int* __restrict__ gbase,
                                                      int* __restrict__ gcursor) {
    __shared__ int sc[256];
    int tid = threadIdx.x;
    int a0 = bcnt[2 * tid], a1 = bcnt[2 * tid + 1];
    int s = a0 + a1;
    sc[tid] = s;
    __syncthreads();
    for (int off = 1; off < 256; off <<= 1) {
        int t = (tid >= off) ? sc[tid - off] : 0;
        __syncthreads();
        sc[tid] += t;
        __syncthreads();
    }
    int ex = sc[tid] - s;
    gbase[2 * tid] = ex;         gcursor[2 * tid] = ex;
    gbase[2 * tid + 1] = ex + a0; gcursor[2 * tid + 1] = ex + a0;
    if (tid == 255) gbase[512] = sc[255];
}

// ---------------- bin: append edges into bucket-contiguous runs ----------------

#define EPB 4096
__global__ __launch_bounds__(256) void bin_kernel(const int* __restrict__ src,
                                                  const int* __restrict__ dst,
                                                  int* __restrict__ gcursor,
                                                  int2* __restrict__ binned, int E) {
    __shared__ int hist[512];
    __shared__ int base[512];
    int tid = threadIdx.x;
    int e0 = blockIdx.x * EPB;
    hist[tid] = 0; hist[tid + 256] = 0;
    __syncthreads();
    int sv[16], dv[16], bv[16];
#pragma unroll
    for (int i = 0; i < 16; ++i) {
        int e = e0 + i * 256 + tid;
        if (e < E) {
            sv[i] = src[e]; dv[i] = dst[e];
            bv[i] = dv[i] >> 7;
            atomicAdd(&hist[bv[i]], 1);
        } else bv[i] = -1;
    }
    __syncthreads();
    {
        int c0 = hist[tid];
        base[tid] = c0 ? atomicAdd(&gcursor[tid], c0) : 0;
        hist[tid] = 0;
        int c1 = hist[tid + 256];
        base[tid + 256] = c1 ? atomicAdd(&gcursor[tid + 256], c1) : 0;
        hist[tid + 256] = 0;
    }
    __syncthreads();
#pragma unroll
    for (int i = 0; i < 16; ++i) {
        if (bv[i] >= 0) {
            int off = atomicAdd(&hist[bv[i]], 1);
            binned[base[bv[i]] + off] = make_int2(sv[i], dv[i]);
        }
    }
}

// ---------------- place: per bucket, derive row_ptr/inv_deg + place col ----------------

__global__ __launch_bounds__(256) void place_kernel(const int2* __restrict__ binned,
                                                    const int* __restrict__ gbase,
                                                    int* __restrict__ row_ptr,
                                                    float* __restrict__ inv_deg,
                                                    int* __restrict__ col,
                                                    int n, int E, int NB) {
    __shared__ int cnt[128];
    __shared__ int sc[128];
    __shared__ int cur[128];
    int b = blockIdx.x, tid = threadIdx.x;
    int node0 = b << 7;
    int node1 = node0 + 128; if (node1 > n) node1 = n;
    int start = gbase[b], end = gbase[b + 1];
    if (tid < 128) cnt[tid] = 0;
    __syncthreads();
    // pass 1: local degree counts
    for (int i = start + tid; i < end; i += 256)
        atomicAdd(&cnt[binned[i].y & 127], 1);
    __syncthreads();
    // scan 128 counts
    if (tid < 128) sc[tid] = cnt[tid];
    __syncthreads();
    for (int off = 1; off < 128; off <<= 1) {
        int t = (tid < 128 && tid >= off) ? sc[tid - off] : 0;
        __syncthreads();
        if (tid < 128) sc[tid] += t;
        __syncthreads();
    }
    if (tid < 128) {
        int nd = node0 + tid;
        if (nd < node1) {
            int c = cnt[tid];
            int base = start + sc[tid] - c;   // exclusive
            row_ptr[nd] = base;
            inv_deg[nd] = 1.0f / (float)((c > 0) ? c : 1);
            cur[tid] = base;
        }
    }
    if (b == NB - 1 && tid == 0) row_ptr[n] = E;
    __syncthreads();
    // pass 2: place
    for (int i = start + tid; i < end; i += 256) {
        int2 e = binned[i];
        int pos = atomicAdd(&cur[e.y & 127], 1);
        col[pos] = e.x;
    }
}

// ---------------- mean aggregation (bf16 in/out, f32 accumulate) ----------------
// one wave per node; 4 groups x 16 lanes x 16B; unroll 2 -> 8 neighbor rows in flight

__global__ void agg_kernel(const short* __restrict__ h, const int* __restrict__ row_ptr,
                           const int* __restrict__ col, const float* __restrict__ inv_deg,
                           short* __restrict__ out, int n) {
    int w = (blockIdx.x * blockDim.x + threadIdx.x) >> 6;
    int lane = threadIdx.x & 63;
    if (w >= n) return;
    int s = row_ptr[w], e = row_ptr[w + 1];
    int g = lane >> 4, l16 = lane & 15;
    float acc[8];
#pragma unroll
    for (int q = 0; q < 8; ++q) acc[q] = 0.f;
    int p = s + g;
    for (; p + 4 < e; p += 8) {
        int j0 = col[p];
        int j1 = col[p + 4];
        bf16x8 v0 = *(const bf16x8*)(h + (size_t)j0 * D + l16 * 8);
        bf16x8 v1 = *(const bf16x8*)(h + (size_t)j1 * D + l16 * 8);
#pragma unroll
        for (int q = 0; q < 8; ++q) acc[q] += b2f(v0[q]);
#pragma unroll
        for (int q = 0; q < 8; ++q) acc[q] += b2f(v1[q]);
    }
    if (p < e) {
        int j = col[p];
        bf16x8 v = *(const bf16x8*)(h + (size_t)j * D + l16 * 8);
#pragma unroll
        for (int q = 0; q < 8; ++q) acc[q] += b2f(v[q]);
    }
#pragma unroll
    for (int q = 0; q < 8; ++q) {
        acc[q] += __shfl_xor(acc[q], 16, 64);
        acc[q] += __shfl_xor(acc[q], 32, 64);
    }
    if (g == 0) {
        float sc = inv_deg[w];
        bf16x8 o;
#pragma unroll
        for (int q = 0; q < 8; ++q) o[q] = f2b(acc[q] * sc);
        *(bf16x8*)(out + (size_t)w * D + l16 * 8) = o;
    }
}

// ---------------- fused dual GEMM, bf16 MFMA ----------------

__global__ __launch_bounds__(256) void sage_mm_mfma(
        const short* __restrict__ Aagg, const short* __restrict__ Hin,
        const short* __restrict__ WlT,  const short* __restrict__ WrT,
        const float* __restrict__ bl,   short* __restrict__ out, int M) {
    __shared__ short lA[128 * SA];
    __shared__ short lW[128 * SA];
    int tid  = threadIdx.x;
    int wave = tid >> 6, lane = tid & 63;
    int row0 = blockIdx.x * 128;
    int mrow = wave * 32;
    int m16  = lane & 15, quad = lane >> 4;

    f32x4 acc[2][8];
#pragma unroll
    for (int i = 0; i < 2; ++i)
#pragma unroll
        for (int j = 0; j < 8; ++j) acc[i][j] = (f32x4){0.f, 0.f, 0.f, 0.f};

#pragma unroll
    for (int half = 0; half < 2; ++half) {
        const short* A = half ? Hin : Aagg;
        const short* W = half ? WrT : WlT;
#pragma unroll
        for (int it = 0; it < 8; ++it) {
            int idx = it * 256 + tid;
            int r = idx >> 4, c8 = (idx & 15) << 3;
            bf16x8 va = {0, 0, 0, 0, 0, 0, 0, 0};
            int gr = row0 + r;
            if (gr < M) va = *(const bf16x8*)(A + (size_t)gr * D + c8);
            *(bf16x8*)(&lA[r * SA + c8]) = va;
            bf16x8 vw = *(const bf16x8*)(W + r * D + c8);
            *(bf16x8*)(&lW[r * SA + c8]) = vw;
        }
        __syncthreads();
#pragma unroll
        for (int ks = 0; ks < 4; ++ks) {
            int kb = ks * 32 + quad * 8;
            bf16x8 a0 = *(const bf16x8*)(&lA[(mrow +      m16) * SA + kb]);
            bf16x8 a1 = *(const bf16x8*)(&lA[(mrow + 16 + m16) * SA + kb]);
#pragma unroll
            for (int nt = 0; nt < 8; ++nt) {
                bf16x8 b = *(const bf16x8*)(&lW[(nt * 16 + m16) * SA + kb]);
                acc[0][nt] = __builtin_amdgcn_mfma_f32_16x16x32_bf16(a0, b, acc[0][nt], 0, 0, 0);
                acc[1][nt] = __builtin_amdgcn_mfma_f32_16x16x32_bf16(a1, b, acc[1][nt], 0, 0, 0);
            }
        }
        __syncthreads();
    }
#pragma unroll
    for (int mt = 0; mt < 2; ++mt) {
#pragma unroll
        for (int r = 0; r < 4; ++r) {
            int grow = row0 + mrow + mt * 16 + quad * 4 + r;
            if (grow < M) {
#pragma unroll
                for (int nt = 0; nt < 8; ++nt) {
                    int gcol = nt * 16 + m16;
                    float v = acc[mt][nt][r] + bl[gcol];
                    out[(size_t)grow * D + gcol] = f2b(fmaxf(v, 0.f));
                }
            }
        }
    }
}

// ---------------- fused global-max-pool + MLP head, one block per graph ----------------

__global__ __launch_bounds__(256) void poolhead_kernel(
        const short* __restrict__ h, const int* __restrict__ batch,
        const float* __restrict__ x,
        const float* __restrict__ W_f1, const float* __restrict__ b_f1,
        const float* __restrict__ W_f2, const float* __restrict__ b_f2,
        const float* __restrict__ W_sm, const float* __restrict__ b_sm,
        const float* __restrict__ W_news, const float* __restrict__ b_news,
        const float* __restrict__ W_cat, const float* __restrict__ b_cat,
        float* __restrict__ out, int n) {
    int g = blockIdx.x;
    int tid = threadIdx.x;
    int f = tid & 127, half = tid >> 7;
    __shared__ float pm[256];
    __shared__ float p[128], t1[256], t2[128], hs[2], nw[2];
    // segment bounds via binary search on sorted batch
    int lo = 0, hi = n;
    while (lo < hi) { int m = (lo + hi) >> 1; if (batch[m] < g) lo = m + 1; else hi = m; }
    int start = lo;
    hi = n;
    while (lo < hi) { int m = (lo + hi) >> 1; if (batch[m] < g + 1) lo = m + 1; else hi = m; }
    int end = lo;
    // max pool: two threads per feature
    float m = -3.4e38f;
    for (int i = start + half; i < end; i += 2) m = fmaxf(m, b2f(h[(size_t)i * D + f]));
    pm[tid] = m;
    __syncthreads();
    if (tid < 128) p[tid] = fmaxf(pm[tid], pm[tid + 128]);
    __syncthreads();
    // fc1: 128 -> 256
    float a1 = b_f1[tid];
    for (int k = 0; k < 128; ++k) a1 += p[k] * W_f1[k * 256 + tid];
    t1[tid] = fmaxf(a1, 0.f);
    __syncthreads();
    // fc2: 256 -> 128
    if (tid < 128) {
        float a2 = b_f2[tid];
        for (int k = 0; k < 256; ++k) a2 += t1[k] * W_f2[k * 128 + tid];
        t2[tid] = fmaxf(a2, 0.f);
    }
    __syncthreads();
    if (tid < 2) {
        float a3 = b_sm[tid];
        for (int k = 0; k < 128; ++k) a3 += t2[k] * W_sm[k * 2 + tid];
        hs[tid] = fmaxf(a3, 0.f);
        const float* xr = x + (size_t)start * D;   // root = first node of graph
        float a4 = b_news[tid];
        for (int k = 0; k < 128; ++k) a4 += xr[k] * W_news[k * 2 + tid];
        nw[tid] = fmaxf(a4, 0.f);
    }
    __syncthreads();
    if (tid == 0) {
        float o = b_cat[0] + hs[0] * W_cat[0] + hs[1] * W_cat[1]
                           + nw[0] * W_cat[2] + nw[1] * W_cat[3];
        out[g] = 1.0f / (1.0f + __expf(-o));
    }
}

// ---------------- launch ----------------

extern "C" void kernel_launch(void* const* d_in, const int* in_sizes, int n_in,
                              void* d_out, int out_size, void* d_ws, size_t ws_size,
                              hipStream_t stream) {
    const float* x      = (const float*)d_in[0];
    const int*   edge   = (const int*)d_in[1];
    const int*   batch  = (const int*)d_in[2];
    const float* Wl1 = (const float*)d_in[3];
    const float* Wr1 = (const float*)d_in[4];
    const float* bl1 = (const float*)d_in[5];
    const float* Wl2 = (const float*)d_in[6];
    const float* Wr2 = (const float*)d_in[7];
    const float* bl2 = (const float*)d_in[8];
    const float* Wl3 = (const float*)d_in[9];
    const float* Wr3 = (const float*)d_in[10];
    const float* bl3 = (const float*)d_in[11];
    const float* W_f1 = (const float*)d_in[12];
    const float* b_f1 = (const float*)d_in[13];
    const float* W_f2 = (const float*)d_in[14];
    const float* b_f2 = (const float*)d_in[15];
    const float* W_sm = (const float*)d_in[16];
    const float* b_sm = (const float*)d_in[17];
    const float* W_news = (const float*)d_in[18];
    const float* b_news = (const float*)d_in[19];
    const float* W_cat = (const float*)d_in[20];
    const float* b_cat = (const float*)d_in[21];
    float* out = (float*)d_out;

    const int E = in_sizes[1] / 2;
    const int n = in_sizes[2];
    const int B = out_size;

    const int* src = edge;
    const int* dst = edge + E;

    char* ws = (char*)d_ws;
    size_t off = 0;
    auto carve = [&](size_t bytes) {
        void* pt = ws + off;
        off = (off + bytes + 255) & ~(size_t)255;
        return pt;
    };
    int*   row_ptr = (int*)carve((size_t)(n + 1) * 4);
    float* inv_deg = (float*)carve((size_t)n * 4);
    int*   col     = (int*)carve((size_t)E * 4);
    int*   bcnt    = (int*)carve((size_t)512 * 4);
    int*   gbase   = (int*)carve((size_t)513 * 4);
    int*   gcursor = (int*)carve((size_t)512 * 4);
    int2*  binned  = (int2*)carve((size_t)E * 8);
    short* xb      = (short*)carve((size_t)n * D * 2);
    short* aggb    = (short*)carve((size_t)n * D * 2);
    short* hA      = (short*)carve((size_t)n * D * 2);
    short* hB      = (short*)carve((size_t)n * D * 2);
    short* Wt[6];
    for (int i = 0; i < 6; ++i) Wt[i] = (short*)carve((size_t)D * D * 2);
    (void)ws_size;

    // --- prep: conv_x + conv_w + bucket histogram ---
    hipMemsetAsync(bcnt, 0, 512 * 4, stream);   // tiny
    PrepArgs pa;
    pa.x = x; pa.xb = xb; pa.total4 = n * D / 4;
    pa.xb_blocks = (pa.total4 + 255) / 256;
    pa.w[0] = Wl1; pa.w[1] = Wr1; pa.w[2] = Wl2; pa.w[3] = Wr2; pa.w[4] = Wl3; pa.w[5] = Wr3;
    for (int i = 0; i < 6; ++i) pa.wo[i] = Wt[i];
    pa.w_blocks = (6 * D * D) / 1024;           // 4 elems/thread, exact
    pa.dst = dst; pa.bcnt = bcnt; pa.E = E;
    int h_blocks = (E + 4095) / 4096;
    prep_kernel<<<pa.xb_blocks + pa.w_blocks + h_blocks, 256, 0, stream>>>(pa);

    // --- CSR ---
    int NB = (n + 127) / 128;   // <=512
    scan512_kernel<<<1, 256, 0, stream>>>(bcnt, gbase, gcursor);
    bin_kernel<<<(E + EPB - 1) / EPB, 256, 0, stream>>>(src, dst, gcursor, binned, E);
    place_kernel<<<NB, 256, 0, stream>>>(binned, gbase, row_ptr, inv_deg, col, n, E, NB);

    int agg_blocks = (n * 64 + 255) / 256;
    int mm_blocks  = (n + 127) / 128;

    agg_kernel<<<agg_blocks, 256, 0, stream>>>(xb, row_ptr, col, inv_deg, aggb, n);
    sage_mm_mfma<<<mm_blocks, 256, 0, stream>>>(aggb, xb, Wt[0], Wt[1], bl1, hA, n);
    agg_kernel<<<agg_blocks, 256, 0, stream>>>(hA, row_ptr, col, inv_deg, aggb, n);
    sage_mm_mfma<<<mm_blocks, 256, 0, stream>>>(aggb, hA, Wt[2], Wt[3], bl2, hB, n);
    agg_kernel<<<agg_blocks, 256, 0, stream>>>(hB, row_ptr, col, inv_deg, aggb, n);
    sage_mm_mfma<<<mm_blocks, 256, 0, stream>>>(aggb, hB, Wt[4], Wt[5], bl3, hA, n);

    poolhead_kernel<<<B, 256, 0, stream>>>(hA, batch, x,
                                           W_f1, b_f1, W_f2, b_f2, W_sm, b_sm,
                                           W_news, b_news, W_cat, b_cat, out, n);
}